// Round 8
// baseline (136.340 us; speedup 1.0000x reference)
//
#include <hip/hip_runtime.h>

// ScalarDistanceDeepSet: B=32, N=256, pairs P=32640 (upper tri, k=1)
// phi: s -> relu(s*W1+b1)[64] -> relu(.@W2+b2)[128], masked sum over pairs
// rho: pooled[128] -> 256 -> 128 -> 64
//
// g_e(s) is piecewise-linear in s with 64 shared breakpoints. Tables
// alpha/beta[seg][e] make per-(pair,channel) work 1 FMA + 1 max. EXACT.
//
// R14: phi (~33us) is the last big controllable cost (2 harness fills
// ~83us are the floor). R4's counters prove ~160cyc SERIAL chain/visit:
// VGPR_Count=12 -> compiler sinks each ds_read_b64 to its use (zero
// in-flight loads); R12's source batching was neutral because nothing
// FORCES in-flight loads. R14 adds __builtin_amdgcn_sched_barrier(0)
// between a cluster's ds_read issues and its FMAs: load-sinking becomes
// illegal, 4-8 float2 stay live, counted lgkmcnt waits (m97 pattern).
// Clusters: 4-visit (solo row) and 8-visit (row A + row B interleaved,
// separate accA/accB -- reorder OK, harness tolerance per R4/R12).
// ~40 VGPR expected, <=64 so (512,8) keeps 4 blocks/CU. build/rho = R13.

#define NB 32
#define NN 256
#define PHI2 128
#define SEGS 65

// ---------------- Kernel A: build tables ----------------
// grid: 65 blocks (one per segment), 128 threads (one per output channel e)
// table2[h][seg][l] = {alpha, beta} for channel h*64+l
__global__ __launch_bounds__(128) void build_tables(
    const float* __restrict__ W1, const float* __restrict__ b1,
    const float* __restrict__ W2, const float* __restrict__ b2,
    float2* __restrict__ table2,   // [2][SEGS][64]
    float* __restrict__ tsort, float* __restrict__ pooled) {
  __shared__ float w2_s[64 * PHI2];   // 32 KB
  __shared__ float t_s[64], w1_s[64], b1_s[64];
  __shared__ int cat_s[64], rank_s[64];
  const int tid = threadIdx.x;
  const int seg = blockIdx.x;
  const float4* W2v = (const float4*)W2;
  float4* w2v = (float4*)w2_s;
  for (int i = tid; i < 64 * PHI2 / 4; i += 128) w2v[i] = W2v[i];
  if (tid < 64) {
    float w = W1[tid], bb = b1[tid];
    w1_s[tid] = w; b1_s[tid] = bb;
    int cat; float t;
    if (w > 0.f)      { cat = 0; t = -bb / w; }   // active for s > t
    else if (w < 0.f) { cat = 1; t = -bb / w; }   // active for s < t
    else              { cat = (bb > 0.f) ? 2 : 3; t = 0.f; } // always/never
    t_s[tid] = t; cat_s[tid] = cat;
  }
  __syncthreads();
  if (tid < 64) {
    float t = t_s[tid]; int r = 0;
    for (int k = 0; k < 64; ++k) {
      float tk = t_s[k];
      r += (tk < t) || (tk == t && k < tid);   // stable rank
    }
    rank_s[tid] = r;
    if (seg == 0) tsort[r] = t;
  }
  __syncthreads();
  // channel e = tid. seg(s) = #breakpoints strictly < s.
  float a = 0.f, bsum = b2[tid];
#pragma unroll 8
  for (int j = 0; j < 64; ++j) {
    int cat = cat_s[j], r = rank_s[j];
    bool act = (cat == 0) ? (seg > r) : (cat == 1) ? (seg <= r) : (cat == 2);
    float w2 = w2_s[j * PHI2 + tid];
    float m = act ? 1.f : 0.f;
    a    = fmaf(m * w1_s[j], w2, a);
    bsum = fmaf(m * b1_s[j], w2, bsum);
  }
  const int h = tid >> 6, l = tid & 63;
  table2[((h * SEGS) + seg) * 64 + l] = make_float2(a, bsum);
  if (seg == 0) {
    for (int i = tid; i < NB * PHI2; i += 128) pooled[i] = 0.f;
  }
}

__device__ __forceinline__ float bcast(float v, int L) {
  return __int_as_float(__builtin_amdgcn_readlane(__float_as_int(v), L));
}
__device__ __forceinline__ int segof(float tv, float s) {
  return (int)__popcll(__ballot(tv < s));
}

// Single visit (used for ragged edges only, <=6 per row).
__device__ __forceinline__ void visit(float comp, int L, float tv, int lane,
                                      const float2* ab_s, float& acc) {
  float s = bcast(comp, L);
  float2 p = ab_s[segof(tv, s) * 64 + lane];
  acc += fmaxf(fmaf(p.x, s, p.y), 0.f);
}
__device__ __forceinline__ void visit_dyn(const float4& f4, int j, float tv,
                                          int lane, const float2* ab_s,
                                          float& acc) {
  int c = j & 3;
  float comp = (c == 0) ? f4.x : (c == 1) ? f4.y : (c == 2) ? f4.z : f4.w;
  visit(comp, j >> 2, tv, lane, ab_s, acc);
}

// 4-visit cluster, one row: issue 4 ds_read_b64, FENCE, then 4 fma/max.
// The sched_barrier makes load-sinking illegal -> 4 loads stay in flight.
__device__ __forceinline__ void group4(const float4& f4, int L, float tv,
                                       int lane, const float2* ab_s,
                                       float& acc) {
  float s0 = bcast(f4.x, L), s1 = bcast(f4.y, L);
  float s2 = bcast(f4.z, L), s3 = bcast(f4.w, L);
  int p0 = segof(tv, s0), p1 = segof(tv, s1);
  int p2 = segof(tv, s2), p3 = segof(tv, s3);
  float2 q0 = ab_s[p0 * 64 + lane];
  float2 q1 = ab_s[p1 * 64 + lane];
  float2 q2 = ab_s[p2 * 64 + lane];
  float2 q3 = ab_s[p3 * 64 + lane];
  __builtin_amdgcn_sched_barrier(0);
  acc += fmaxf(fmaf(q0.x, s0, q0.y), 0.f);
  acc += fmaxf(fmaf(q1.x, s1, q1.y), 0.f);
  acc += fmaxf(fmaf(q2.x, s2, q2.y), 0.f);
  acc += fmaxf(fmaf(q3.x, s3, q3.y), 0.f);
}

// 8-visit cluster, two independent rows (separate accumulators):
// 8 ds_read_b64 in flight, one fence, 8 fma/max.
__device__ __forceinline__ void group4x2(const float4& fa, int LA,
                                         const float4& fb, int LB, float tv,
                                         int lane, const float2* ab_s,
                                         float& accA, float& accB) {
  float a0 = bcast(fa.x, LA), a1 = bcast(fa.y, LA);
  float a2 = bcast(fa.z, LA), a3 = bcast(fa.w, LA);
  float b0 = bcast(fb.x, LB), b1 = bcast(fb.y, LB);
  float b2 = bcast(fb.z, LB), b3 = bcast(fb.w, LB);
  int pa0 = segof(tv, a0), pa1 = segof(tv, a1);
  int pa2 = segof(tv, a2), pa3 = segof(tv, a3);
  int pb0 = segof(tv, b0), pb1 = segof(tv, b1);
  int pb2 = segof(tv, b2), pb3 = segof(tv, b3);
  float2 qa0 = ab_s[pa0 * 64 + lane];
  float2 qa1 = ab_s[pa1 * 64 + lane];
  float2 qa2 = ab_s[pa2 * 64 + lane];
  float2 qa3 = ab_s[pa3 * 64 + lane];
  float2 qb0 = ab_s[pb0 * 64 + lane];
  float2 qb1 = ab_s[pb1 * 64 + lane];
  float2 qb2 = ab_s[pb2 * 64 + lane];
  float2 qb3 = ab_s[pb3 * 64 + lane];
  __builtin_amdgcn_sched_barrier(0);
  accA += fmaxf(fmaf(qa0.x, a0, qa0.y), 0.f);
  accA += fmaxf(fmaf(qa1.x, a1, qa1.y), 0.f);
  accA += fmaxf(fmaf(qa2.x, a2, qa2.y), 0.f);
  accA += fmaxf(fmaf(qa3.x, a3, qa3.y), 0.f);
  accB += fmaxf(fmaf(qb0.x, b0, qb0.y), 0.f);
  accB += fmaxf(fmaf(qb1.x, b1, qb1.y), 0.f);
  accB += fmaxf(fmaf(qb2.x, b2, qb2.y), 0.f);
  accB += fmaxf(fmaf(qb3.x, b3, qb3.y), 0.f);
}

// Row bounds. Valid cols j in [i0+1, len-1]; full 4-groups [fLo, fHi].
__device__ __forceinline__ void bounds(int i0, int len, int& jlo, int& jhi,
                                       int& fLo, int& fHi) {
  jlo = i0 + 1; jhi = len - 1;
  fLo = (jlo + 3) >> 2;
  fHi = (jhi >= 3) ? ((jhi - 3) >> 2) : -1;
}

// Ragged-edge visits for one row (whole row if it has no full group).
__device__ __forceinline__ void edges(const float4& f4, int jlo, int jhi,
                                      int fLo, int fHi, float tv, int lane,
                                      const float2* ab_s, float& acc) {
  if (fLo > fHi) {
    for (int j = jlo; j <= jhi; ++j) visit_dyn(f4, j, tv, lane, ab_s, acc);
    return;
  }
  for (int j = jlo; j < fLo * 4; ++j) visit_dyn(f4, j, tv, lane, ab_s, acc);
  for (int j = fHi * 4 + 4; j <= jhi; ++j)
    visit_dyn(f4, j, tv, lane, ab_s, acc);
}

// ---------------- Kernel B: phi + masked pooling ----------------
// grid: (16 row-chunks, 2 halves, 32 batches) x 512 threads (8 waves).
// Wave w owns row r = chunk*8+w (0..127) and its mirror 254-r (balanced).
__global__ __launch_bounds__(512, 8) void phi_pool(
    const float* __restrict__ dm, const int* __restrict__ lengths,
    const float2* __restrict__ table2, const float* __restrict__ tsort,
    float* __restrict__ pooled) {
  __shared__ float2 ab_s[SEGS * 64];   // 33,280 B -> 4 blocks/CU
  const int chunk = blockIdx.x;   // 0..15
  const int h     = blockIdx.y;   // channel half
  const int b     = blockIdx.z;   // batch
  const int tid = threadIdx.x;
  const int lane = tid & 63, w = tid >> 6;

  const int len = lengths[b];
  // block-uniform early exit: no primary row (8c) and no mirror row (247-8c)
  if (8 * chunk > len - 2 && 247 - 8 * chunk > len - 2) return;

  const float2* tg = table2 + h * SEGS * 64;
  for (int i = tid; i < SEGS * 64; i += 512) ab_s[i] = tg[i];
  __syncthreads();

  const float tv = tsort[lane];      // breakpoint in register, one per lane
  const float* dmb = dm + (size_t)b * (NN * NN);

  const int rA = chunk * 8 + w;      // 0..127
  const int rB = 254 - rA;           // 127..254
  // issue both full-row loads up-front (always address-valid)
  const float4 fA = ((const float4*)(dmb + rA * NN))[lane];
  const float4 fB = ((const float4*)(dmb + rB * NN))[lane];

  const bool hasA = (rA <= len - 2);
  const bool hasB = (rB != rA && rB <= len - 2);

  int jloA, jhiA, fLoA, fHiA, jloB, jhiB, fLoB, fHiB;
  if (hasA) bounds(rA, len, jloA, jhiA, fLoA, fHiA);
  else { jloA = 1; jhiA = 0; fLoA = 0; fHiA = -1; }
  if (hasB) bounds(rB, len, jloB, jhiB, fLoB, fHiB);
  else { jloB = 1; jhiB = 0; fLoB = 0; fHiB = -1; }

  float accA = 0.f, accB = 0.f;
  if (hasA) edges(fA, jloA, jhiA, fLoA, fHiA, tv, lane, ab_s, accA);
  if (hasB) edges(fB, jloB, jhiB, fLoB, fHiB, tv, lane, ab_s, accB);

  // interleaved main loops: 8 independent ds_read_b64 in flight per iter
  int LA = fLoA, LB = fLoB;
  for (; LA <= fHiA && LB <= fHiB; ++LA, ++LB)
    group4x2(fA, LA, fB, LB, tv, lane, ab_s, accA, accB);
#pragma unroll 2
  for (; LA <= fHiA; ++LA) group4(fA, LA, tv, lane, ab_s, accA);
#pragma unroll 2
  for (; LB <= fHiB; ++LB) group4(fB, LB, tv, lane, ab_s, accB);

  atomicAdd(&pooled[b * PHI2 + h * 64 + lane], accA + accB);
}

// ---------------- Kernel C: rho MLP (no weight staging) ----------------
// grid: 32 blocks (one per batch), 256 threads. Weights read directly from
// global, coalesced (consecutive tids -> consecutive addresses); unroll-8
// keeps 8 L2-hot loads in flight. Same k-ascending fmaf order as always.
__global__ __launch_bounds__(256) void rho_mlp(
    const float* __restrict__ pooled,
    const float* __restrict__ W3, const float* __restrict__ b3,
    const float* __restrict__ W4, const float* __restrict__ b4,
    const float* __restrict__ W5, const float* __restrict__ b5,
    float* __restrict__ out) {
  __shared__ float p_s[128], r1_s[256], r2_s[128];
  const int b = blockIdx.x, tid = threadIdx.x;
  if (tid < 128) p_s[tid] = pooled[b * 128 + tid];
  __syncthreads();
  {
    float acc = b3[tid];
#pragma unroll 8
    for (int k = 0; k < 128; ++k) acc = fmaf(p_s[k], W3[k * 256 + tid], acc);
    r1_s[tid] = fmaxf(acc, 0.f);
  }
  __syncthreads();
  if (tid < 128) {
    float acc = b4[tid];
#pragma unroll 8
    for (int k = 0; k < 256; ++k) acc = fmaf(r1_s[k], W4[k * 128 + tid], acc);
    r2_s[tid] = fmaxf(acc, 0.f);
  }
  __syncthreads();
  if (tid < 64) {
    float acc = b5[tid];
#pragma unroll 8
    for (int k = 0; k < 128; ++k) acc = fmaf(r2_s[k], W5[k * 64 + tid], acc);
    out[b * 64 + tid] = acc;
  }
}

extern "C" void kernel_launch(void* const* d_in, const int* in_sizes, int n_in,
                              void* d_out, int out_size, void* d_ws, size_t ws_size,
                              hipStream_t stream) {
  const float* dm      = (const float*)d_in[0];
  const int*   lengths = (const int*)d_in[1];
  const float* W1 = (const float*)d_in[2];
  const float* b1 = (const float*)d_in[3];
  const float* W2 = (const float*)d_in[4];
  const float* b2 = (const float*)d_in[5];
  const float* W3 = (const float*)d_in[6];
  const float* b3 = (const float*)d_in[7];
  const float* W4 = (const float*)d_in[8];
  const float* b4 = (const float*)d_in[9];
  const float* W5 = (const float*)d_in[10];
  const float* b5 = (const float*)d_in[11];

  float* ws = (float*)d_ws;
  float2* table2 = (float2*)ws;          // 2*65*64 float2 = 16640 floats
  float* tsort   = ws + 16640;           // 64
  float* pooled  = ws + 16704;           // 32*128 = 4096

  build_tables<<<SEGS, 128, 0, stream>>>(W1, b1, W2, b2, table2, tsort, pooled);
  phi_pool<<<dim3(16, 2, NB), 512, 0, stream>>>(dm, lengths, table2, tsort, pooled);
  rho_mlp<<<NB, 256, 0, stream>>>(pooled, W3, b3, W4, b4, W5, b5, (float*)d_out);
}

// Round 9
// 129.571 us; speedup vs baseline: 1.0522x; 1.0522x over previous
//
#include <hip/hip_runtime.h>

// ScalarDistanceDeepSet: B=32, N=256, pairs P=32640 (upper tri, k=1)
// phi: s -> relu(s*W1+b1)[64] -> relu(.@W2+b2)[128], masked sum over pairs
// rho: pooled[128] -> 256 -> 128 -> 64
//
// g_e(s) is piecewise-linear in s with 64 shared breakpoints. Tables
// alpha/beta[seg][e] make per-(pair,channel) work 1 FMA + 1 max. EXACT.
//
// R15: R12/R14 proved intra-visit LDS latency is already TLP-hidden (both
// pipelining attempts neutral) -> phi cost = visit COUNT x occupancy. Merge
// the channel halves (one ds_read_b128 serves both -> 262K visits instead
// of 524K, shared readlane/ballot/addr). R7 tried this and lost because
// 66.5KB @ 512-thr blocks = 16 waves/CU (50% occ). Fix: 1024-THREAD
// blocks: 66.5KB x 2 blocks/CU = 133KB < 160KB, 32 waves/CU = FULL
// occupancy. Grid (16,32)=512 blocks = exact residency; transposed row
// map r = w*16 + chunk balances block durations (block c's longest row
// is c). Inner loop stays the R0-family unbatched visit (proven lean
// codegen); (1024,8) caps VGPR at 64, expected ~24-32. build writes the
// interleaved float4 table (R7-proven); rho = R13 (no staging).

#define NB 32
#define NN 256
#define PHI2 128
#define SEGS 65

// ---------------- Kernel A: build tables ----------------
// grid: 65 blocks (one per segment), 128 threads (one per output channel e)
// table viewed as float4[seg][l] = (a_l, b_l, a_{l+64}, b_{l+64})
__global__ __launch_bounds__(128) void build_tables(
    const float* __restrict__ W1, const float* __restrict__ b1,
    const float* __restrict__ W2, const float* __restrict__ b2,
    float2* __restrict__ table2,   // float2[(seg*64+l)*2 + h]
    float* __restrict__ tsort, float* __restrict__ pooled) {
  __shared__ float w2_s[64 * PHI2];   // 32 KB
  __shared__ float t_s[64], w1_s[64], b1_s[64];
  __shared__ int cat_s[64], rank_s[64];
  const int tid = threadIdx.x;
  const int seg = blockIdx.x;
  const float4* W2v = (const float4*)W2;
  float4* w2v = (float4*)w2_s;
  for (int i = tid; i < 64 * PHI2 / 4; i += 128) w2v[i] = W2v[i];
  if (tid < 64) {
    float w = W1[tid], bb = b1[tid];
    w1_s[tid] = w; b1_s[tid] = bb;
    int cat; float t;
    if (w > 0.f)      { cat = 0; t = -bb / w; }   // active for s > t
    else if (w < 0.f) { cat = 1; t = -bb / w; }   // active for s < t
    else              { cat = (bb > 0.f) ? 2 : 3; t = 0.f; } // always/never
    t_s[tid] = t; cat_s[tid] = cat;
  }
  __syncthreads();
  if (tid < 64) {
    float t = t_s[tid]; int r = 0;
    for (int k = 0; k < 64; ++k) {
      float tk = t_s[k];
      r += (tk < t) || (tk == t && k < tid);   // stable rank
    }
    rank_s[tid] = r;
    if (seg == 0) tsort[r] = t;
  }
  __syncthreads();
  // channel e = tid. seg(s) = #breakpoints strictly < s.
  float a = 0.f, bsum = b2[tid];
#pragma unroll 8
  for (int j = 0; j < 64; ++j) {
    int cat = cat_s[j], r = rank_s[j];
    bool act = (cat == 0) ? (seg > r) : (cat == 1) ? (seg <= r) : (cat == 2);
    float w2 = w2_s[j * PHI2 + tid];
    float m = act ? 1.f : 0.f;
    a    = fmaf(m * w1_s[j], w2, a);
    bsum = fmaf(m * b1_s[j], w2, bsum);
  }
  const int h = tid >> 6, l = tid & 63;
  table2[(seg * 64 + l) * 2 + h] = make_float2(a, bsum);
  if (seg == 0) {
    for (int i = tid; i < NB * PHI2; i += 128) pooled[i] = 0.f;
  }
}

__device__ __forceinline__ float bcast(float v, int L) {
  return __int_as_float(__builtin_amdgcn_readlane(__float_as_int(v), L));
}
__device__ __forceinline__ int segof(float tv, float s) {
  return (int)__popcll(__ballot(tv < s));
}

// One (pair) visit covering BOTH channel halves: broadcast s from lane L
// (uniform), segment via ballot over register-held breakpoints, one
// ds_read_b128 -> (a_lo,b_lo,a_hi,b_hi). 1 readlane/ballot per PAIR.
__device__ __forceinline__ void visit(float comp, int L, float tv, int lane,
                                      const float4* ab_s,
                                      float& a0, float& a1) {
  float s = bcast(comp, L);
  float4 p = ab_s[segof(tv, s) * 64 + lane];
  a0 += fmaxf(fmaf(p.x, s, p.y), 0.f);
  a1 += fmaxf(fmaf(p.z, s, p.w), 0.f);
}

// Dynamic-component visit for ragged row edges (<=6 per row).
__device__ __forceinline__ void visit_dyn(const float4& f4, int j, float tv,
                                          int lane, const float4* ab_s,
                                          float& a0, float& a1) {
  int c = j & 3;
  float comp = (c == 0) ? f4.x : (c == 1) ? f4.y : (c == 2) ? f4.z : f4.w;
  visit(comp, j >> 2, tv, lane, ab_s, a0, a1);
}

// Process one row: f4 holds the full 256-float row across the wave
// (lane holds cols 4*lane..4*lane+3). Valid cols j in [i0+1, len-1].
// Same skeleton as R0 (proven codegen), merged-half visits.
__device__ __forceinline__ void do_row(const float4& f4, int i0, int len,
                                       float tv, int lane,
                                       const float4* ab_s,
                                       float& a0, float& a1) {
  const int jlo = i0 + 1, jhi = len - 1;   // inclusive; jhi >= jlo guaranteed
  const int fullLo = (jlo + 3) >> 2;       // first fully-valid 4-group
  const int fullHi = (jhi >= 3) ? ((jhi - 3) >> 2) : -1;  // last fully-valid
  if (fullLo > fullHi) {
    for (int j = jlo; j <= jhi; ++j) visit_dyn(f4, j, tv, lane, ab_s, a0, a1);
    return;
  }
  // low ragged edge
  for (int j = jlo; j < fullLo * 4; ++j)
    visit_dyn(f4, j, tv, lane, ab_s, a0, a1);
  // interior full groups: uniform L in SGPR, static components
#pragma unroll 4
  for (int L = fullLo; L <= fullHi; ++L) {
    visit(f4.x, L, tv, lane, ab_s, a0, a1);
    visit(f4.y, L, tv, lane, ab_s, a0, a1);
    visit(f4.z, L, tv, lane, ab_s, a0, a1);
    visit(f4.w, L, tv, lane, ab_s, a0, a1);
  }
  // high ragged edge
  for (int j = fullHi * 4 + 4; j <= jhi; ++j)
    visit_dyn(f4, j, tv, lane, ab_s, a0, a1);
}

// ---------------- Kernel B: phi + masked pooling (merged halves) ----------
// grid: (16 chunks, 32 batches) x 1024 threads (16 waves). Wave w handles
// row r = w*16 + chunk (transposed map -> balanced block durations).
// 66.5KB LDS, 2 blocks/CU, 32 waves/CU (full occupancy).
__global__ __launch_bounds__(1024, 8) void phi_pool(
    const float* __restrict__ dm, const int* __restrict__ lengths,
    const float4* __restrict__ table4, const float* __restrict__ tsort,
    float* __restrict__ pooled) {
  __shared__ float4 ab_s[SEGS * 64];   // 66,560 B
  const int chunk = blockIdx.x;   // 0..15
  const int b     = blockIdx.y;   // batch
  const int tid = threadIdx.x;
  const int lane = tid & 63, w = tid >> 6;   // w: 0..15

  const int len = lengths[b];
  // block-uniform early exit: shortest row in this block is 'chunk'
  if (chunk > len - 2) return;

  for (int i = tid; i < SEGS * 64; i += 1024) ab_s[i] = table4[i];
  __syncthreads();

  const float tv = tsort[lane];      // breakpoint in register, one per lane
  const float* dmb = dm + (size_t)b * (NN * NN);

  const int r = w * 16 + chunk;      // 0..255
  if (r > len - 2) return;           // wave-uniform: no work for this row

  const float4 f4 = ((const float4*)(dmb + r * NN))[lane];
  float a0 = 0.f, a1 = 0.f;
  do_row(f4, r, len, tv, lane, ab_s, a0, a1);

  atomicAdd(&pooled[b * PHI2 + lane], a0);
  atomicAdd(&pooled[b * PHI2 + 64 + lane], a1);
}

// ---------------- Kernel C: rho MLP (no weight staging) ----------------
// grid: 32 blocks (one per batch), 256 threads. Weights read directly from
// global, coalesced; unroll-8 keeps 8 L2-hot loads in flight. Exact order.
__global__ __launch_bounds__(256) void rho_mlp(
    const float* __restrict__ pooled,
    const float* __restrict__ W3, const float* __restrict__ b3,
    const float* __restrict__ W4, const float* __restrict__ b4,
    const float* __restrict__ W5, const float* __restrict__ b5,
    float* __restrict__ out) {
  __shared__ float p_s[128], r1_s[256], r2_s[128];
  const int b = blockIdx.x, tid = threadIdx.x;
  if (tid < 128) p_s[tid] = pooled[b * 128 + tid];
  __syncthreads();
  {
    float acc = b3[tid];
#pragma unroll 8
    for (int k = 0; k < 128; ++k) acc = fmaf(p_s[k], W3[k * 256 + tid], acc);
    r1_s[tid] = fmaxf(acc, 0.f);
  }
  __syncthreads();
  if (tid < 128) {
    float acc = b4[tid];
#pragma unroll 8
    for (int k = 0; k < 256; ++k) acc = fmaf(r1_s[k], W4[k * 128 + tid], acc);
    r2_s[tid] = fmaxf(acc, 0.f);
  }
  __syncthreads();
  if (tid < 64) {
    float acc = b5[tid];
#pragma unroll 8
    for (int k = 0; k < 128; ++k) acc = fmaf(r2_s[k], W5[k * 64 + tid], acc);
    out[b * 64 + tid] = acc;
  }
}

extern "C" void kernel_launch(void* const* d_in, const int* in_sizes, int n_in,
                              void* d_out, int out_size, void* d_ws, size_t ws_size,
                              hipStream_t stream) {
  const float* dm      = (const float*)d_in[0];
  const int*   lengths = (const int*)d_in[1];
  const float* W1 = (const float*)d_in[2];
  const float* b1 = (const float*)d_in[3];
  const float* W2 = (const float*)d_in[4];
  const float* b2 = (const float*)d_in[5];
  const float* W3 = (const float*)d_in[6];
  const float* b3 = (const float*)d_in[7];
  const float* W4 = (const float*)d_in[8];
  const float* b4 = (const float*)d_in[9];
  const float* W5 = (const float*)d_in[10];
  const float* b5 = (const float*)d_in[11];

  float* ws = (float*)d_ws;
  float4* table4 = (float4*)ws;          // 65*64 float4 = 16640 floats
  float* tsort   = ws + 16640;           // 64
  float* pooled  = ws + 16704;           // 32*128 = 4096

  build_tables<<<SEGS, 128, 0, stream>>>(W1, b1, W2, b2, (float2*)table4,
                                         tsort, pooled);
  phi_pool<<<dim3(16, NB), 1024, 0, stream>>>(dm, lengths, table4, tsort,
                                              pooled);
  rho_mlp<<<NB, 256, 0, stream>>>(pooled, W3, b3, W4, b4, W5, b5,
                                  (float*)d_out);
}

// Round 10
// 126.302 us; speedup vs baseline: 1.0795x; 1.0259x over previous
//
#include <hip/hip_runtime.h>

// ScalarDistanceDeepSet: B=32, N=256, pairs P=32640 (upper tri, k=1)
// phi: s -> relu(s*W1+b1)[64] -> relu(.@W2+b2)[128], masked sum over pairs
// rho: pooled[128] -> 256 -> 128 -> 64
//
// g_e(s) is piecewise-linear in s with 64 shared breakpoints. Tables
// alpha/beta[seg][e] make per-(pair,channel) work 1 FMA + 1 max. EXACT.
//
// R16: R15 (merged-half table @ 1024-thr blocks, full 32 waves/CU) won
// 135->129.6. Last proven-pattern lever: build_tables still stages all of
// W2 (32KB LDS) per block x 65 blocks -- same staging anti-pattern that
// cost rho 4us (R13). The seg loop's w2_s[j*PHI2+tid] is exactly
// W2[j*PHI2+tid]: coalesced across tid, L2-hot after block 0, unroll-8
// keeps 8 loads in flight. R16 = R15 verbatim except build reads W2
// direct from global (identical j-ascending fmaf order -> bit-exact).
// phi/rho untouched.

#define NB 32
#define NN 256
#define PHI2 128
#define SEGS 65

// ---------------- Kernel A: build tables (no W2 staging) ----------------
// grid: 65 blocks (one per segment), 128 threads (one per output channel e)
// table viewed as float4[seg][l] = (a_l, b_l, a_{l+64}, b_{l+64})
__global__ __launch_bounds__(128) void build_tables(
    const float* __restrict__ W1, const float* __restrict__ b1,
    const float* __restrict__ W2, const float* __restrict__ b2,
    float2* __restrict__ table2,   // float2[(seg*64+l)*2 + h]
    float* __restrict__ tsort, float* __restrict__ pooled) {
  __shared__ float t_s[64], w1_s[64], b1_s[64];
  __shared__ int cat_s[64], rank_s[64];
  const int tid = threadIdx.x;
  const int seg = blockIdx.x;
  if (tid < 64) {
    float w = W1[tid], bb = b1[tid];
    w1_s[tid] = w; b1_s[tid] = bb;
    int cat; float t;
    if (w > 0.f)      { cat = 0; t = -bb / w; }   // active for s > t
    else if (w < 0.f) { cat = 1; t = -bb / w; }   // active for s < t
    else              { cat = (bb > 0.f) ? 2 : 3; t = 0.f; } // always/never
    t_s[tid] = t; cat_s[tid] = cat;
  }
  __syncthreads();
  if (tid < 64) {
    float t = t_s[tid]; int r = 0;
    for (int k = 0; k < 64; ++k) {
      float tk = t_s[k];
      r += (tk < t) || (tk == t && k < tid);   // stable rank
    }
    rank_s[tid] = r;
    if (seg == 0) tsort[r] = t;
  }
  __syncthreads();
  // channel e = tid. seg(s) = #breakpoints strictly < s.
  // W2 read direct from global: W2[j*PHI2+tid] coalesced across tid,
  // L2-hot; unroll-8 keeps 8 loads in flight. Same fmaf order as ever.
  float a = 0.f, bsum = b2[tid];
#pragma unroll 8
  for (int j = 0; j < 64; ++j) {
    int cat = cat_s[j], r = rank_s[j];
    bool act = (cat == 0) ? (seg > r) : (cat == 1) ? (seg <= r) : (cat == 2);
    float w2 = W2[j * PHI2 + tid];
    float m = act ? 1.f : 0.f;
    a    = fmaf(m * w1_s[j], w2, a);
    bsum = fmaf(m * b1_s[j], w2, bsum);
  }
  const int h = tid >> 6, l = tid & 63;
  table2[(seg * 64 + l) * 2 + h] = make_float2(a, bsum);
  if (seg == 0) {
    for (int i = tid; i < NB * PHI2; i += 128) pooled[i] = 0.f;
  }
}

__device__ __forceinline__ float bcast(float v, int L) {
  return __int_as_float(__builtin_amdgcn_readlane(__float_as_int(v), L));
}
__device__ __forceinline__ int segof(float tv, float s) {
  return (int)__popcll(__ballot(tv < s));
}

// One (pair) visit covering BOTH channel halves: broadcast s from lane L
// (uniform), segment via ballot over register-held breakpoints, one
// ds_read_b128 -> (a_lo,b_lo,a_hi,b_hi). 1 readlane/ballot per PAIR.
__device__ __forceinline__ void visit(float comp, int L, float tv, int lane,
                                      const float4* ab_s,
                                      float& a0, float& a1) {
  float s = bcast(comp, L);
  float4 p = ab_s[segof(tv, s) * 64 + lane];
  a0 += fmaxf(fmaf(p.x, s, p.y), 0.f);
  a1 += fmaxf(fmaf(p.z, s, p.w), 0.f);
}

// Dynamic-component visit for ragged row edges (<=6 per row).
__device__ __forceinline__ void visit_dyn(const float4& f4, int j, float tv,
                                          int lane, const float4* ab_s,
                                          float& a0, float& a1) {
  int c = j & 3;
  float comp = (c == 0) ? f4.x : (c == 1) ? f4.y : (c == 2) ? f4.z : f4.w;
  visit(comp, j >> 2, tv, lane, ab_s, a0, a1);
}

// Process one row: f4 holds the full 256-float row across the wave
// (lane holds cols 4*lane..4*lane+3). Valid cols j in [i0+1, len-1].
__device__ __forceinline__ void do_row(const float4& f4, int i0, int len,
                                       float tv, int lane,
                                       const float4* ab_s,
                                       float& a0, float& a1) {
  const int jlo = i0 + 1, jhi = len - 1;   // inclusive; jhi >= jlo guaranteed
  const int fullLo = (jlo + 3) >> 2;       // first fully-valid 4-group
  const int fullHi = (jhi >= 3) ? ((jhi - 3) >> 2) : -1;  // last fully-valid
  if (fullLo > fullHi) {
    for (int j = jlo; j <= jhi; ++j) visit_dyn(f4, j, tv, lane, ab_s, a0, a1);
    return;
  }
  // low ragged edge
  for (int j = jlo; j < fullLo * 4; ++j)
    visit_dyn(f4, j, tv, lane, ab_s, a0, a1);
  // interior full groups: uniform L in SGPR, static components
#pragma unroll 4
  for (int L = fullLo; L <= fullHi; ++L) {
    visit(f4.x, L, tv, lane, ab_s, a0, a1);
    visit(f4.y, L, tv, lane, ab_s, a0, a1);
    visit(f4.z, L, tv, lane, ab_s, a0, a1);
    visit(f4.w, L, tv, lane, ab_s, a0, a1);
  }
  // high ragged edge
  for (int j = fullHi * 4 + 4; j <= jhi; ++j)
    visit_dyn(f4, j, tv, lane, ab_s, a0, a1);
}

// ---------------- Kernel B: phi + masked pooling (merged halves) ----------
// grid: (16 chunks, 32 batches) x 1024 threads (16 waves). Wave w handles
// row r = w*16 + chunk (transposed map -> balanced block durations).
// 66.5KB LDS, 2 blocks/CU, 32 waves/CU (full occupancy).
__global__ __launch_bounds__(1024, 8) void phi_pool(
    const float* __restrict__ dm, const int* __restrict__ lengths,
    const float4* __restrict__ table4, const float* __restrict__ tsort,
    float* __restrict__ pooled) {
  __shared__ float4 ab_s[SEGS * 64];   // 66,560 B
  const int chunk = blockIdx.x;   // 0..15
  const int b     = blockIdx.y;   // batch
  const int tid = threadIdx.x;
  const int lane = tid & 63, w = tid >> 6;   // w: 0..15

  const int len = lengths[b];
  // block-uniform early exit: shortest row in this block is 'chunk'
  if (chunk > len - 2) return;

  for (int i = tid; i < SEGS * 64; i += 1024) ab_s[i] = table4[i];
  __syncthreads();

  const float tv = tsort[lane];      // breakpoint in register, one per lane
  const float* dmb = dm + (size_t)b * (NN * NN);

  const int r = w * 16 + chunk;      // 0..255
  if (r > len - 2) return;           // wave-uniform: no work for this row

  const float4 f4 = ((const float4*)(dmb + r * NN))[lane];
  float a0 = 0.f, a1 = 0.f;
  do_row(f4, r, len, tv, lane, ab_s, a0, a1);

  atomicAdd(&pooled[b * PHI2 + lane], a0);
  atomicAdd(&pooled[b * PHI2 + 64 + lane], a1);
}

// ---------------- Kernel C: rho MLP (no weight staging) ----------------
// grid: 32 blocks (one per batch), 256 threads. Weights read directly from
// global, coalesced; unroll-8 keeps 8 L2-hot loads in flight. Exact order.
__global__ __launch_bounds__(256) void rho_mlp(
    const float* __restrict__ pooled,
    const float* __restrict__ W3, const float* __restrict__ b3,
    const float* __restrict__ W4, const float* __restrict__ b4,
    const float* __restrict__ W5, const float* __restrict__ b5,
    float* __restrict__ out) {
  __shared__ float p_s[128], r1_s[256], r2_s[128];
  const int b = blockIdx.x, tid = threadIdx.x;
  if (tid < 128) p_s[tid] = pooled[b * 128 + tid];
  __syncthreads();
  {
    float acc = b3[tid];
#pragma unroll 8
    for (int k = 0; k < 128; ++k) acc = fmaf(p_s[k], W3[k * 256 + tid], acc);
    r1_s[tid] = fmaxf(acc, 0.f);
  }
  __syncthreads();
  if (tid < 128) {
    float acc = b4[tid];
#pragma unroll 8
    for (int k = 0; k < 256; ++k) acc = fmaf(r1_s[k], W4[k * 128 + tid], acc);
    r2_s[tid] = fmaxf(acc, 0.f);
  }
  __syncthreads();
  if (tid < 64) {
    float acc = b5[tid];
#pragma unroll 8
    for (int k = 0; k < 128; ++k) acc = fmaf(r2_s[k], W5[k * 64 + tid], acc);
    out[b * 64 + tid] = acc;
  }
}

extern "C" void kernel_launch(void* const* d_in, const int* in_sizes, int n_in,
                              void* d_out, int out_size, void* d_ws, size_t ws_size,
                              hipStream_t stream) {
  const float* dm      = (const float*)d_in[0];
  const int*   lengths = (const int*)d_in[1];
  const float* W1 = (const float*)d_in[2];
  const float* b1 = (const float*)d_in[3];
  const float* W2 = (const float*)d_in[4];
  const float* b2 = (const float*)d_in[5];
  const float* W3 = (const float*)d_in[6];
  const float* b3 = (const float*)d_in[7];
  const float* W4 = (const float*)d_in[8];
  const float* b4 = (const float*)d_in[9];
  const float* W5 = (const float*)d_in[10];
  const float* b5 = (const float*)d_in[11];

  float* ws = (float*)d_ws;
  float4* table4 = (float4*)ws;          // 65*64 float4 = 16640 floats
  float* tsort   = ws + 16640;           // 64
  float* pooled  = ws + 16704;           // 32*128 = 4096

  build_tables<<<SEGS, 128, 0, stream>>>(W1, b1, W2, b2, (float2*)table4,
                                         tsort, pooled);
  phi_pool<<<dim3(16, NB), 1024, 0, stream>>>(dm, lengths, table4, tsort,
                                              pooled);
  rho_mlp<<<NB, 256, 0, stream>>>(pooled, W3, b3, W4, b4, W5, b5,
                                  (float*)d_out);
}